// Round 8
// baseline (233.644 us; speedup 1.0000x reference)
//
#include <hip/hip_runtime.h>
#include <math.h>

#define S_LEN 2048
#define D_DIM 128
#define BHN   32
#define NKT   32   // KV tiles of 64
#define NQT   32   // Q tiles of 64
#define NGRP  8    // per-XCD work groups
#define ITEMS_PER_GRP 128   // 4 bh x 32 qi
#define LOG2E 1.44269504088896340736f

typedef _Float16 f16;
typedef __attribute__((ext_vector_type(4))) _Float16 f16x4;
typedef __attribute__((ext_vector_type(8))) _Float16 f16x8;
typedef __attribute__((ext_vector_type(4))) float    f32x4;
typedef __attribute__((ext_vector_type(16))) float   f32x16;

// per-XCD-group work counters (zeroed by prep_kernel, consumed by attn_kernel)
__device__ int g_counters[NGRP];

__device__ __forceinline__ void async_cp16(const void* g, void* l) {
  __builtin_amdgcn_global_load_lds(
      (const __attribute__((address_space(1))) unsigned int*)g,
      (__attribute__((address_space(3))) unsigned int*)l,
      16, 0, 0);
}

__device__ __forceinline__ uint32_t pk2(float a, float b) {
  f16 h[2] = {(f16)a, (f16)b};
  uint32_t u; __builtin_memcpy(&u, h, 4); return u;
}

// ---- fused prepass: one block per (bh, jt) 64-row tile (UNCHANGED; proven).
__global__ __launch_bounds__(256) void prep_kernel(const float* __restrict__ k,
                                                   const float* __restrict__ v,
                                                   f16* __restrict__ kw,
                                                   f16* __restrict__ vtw) {
  __shared__ f16 Vimg[D_DIM * 64];   // 16 KB, final swizzled V^T image

  if (blockIdx.x == 0 && threadIdx.x < NGRP) g_counters[threadIdx.x] = 0;

  const int bx = blockIdx.x;
  const int bh = bx >> 5;
  const int jt = bx & 31;
  const int t  = threadIdx.x;

  // ---- K: fp32 -> f16 swizzled tile [r(64)][chunk'(16)][8], chunk' = kd^(r&15)
  {
    const float* kbase = k + ((size_t)bh * S_LEN + jt * 64) * D_DIM;
    f16* ktile = kw + (((size_t)bh * NKT + jt) * 64) * (size_t)D_DIM;
#pragma unroll
    for (int i = 0; i < 4; ++i) {
      int unit = i * 256 + t;
      int kd = unit & 15;
      int r  = unit >> 4;
      const float* src = kbase + r * D_DIM + kd * 8;
      float4 a = *(const float4*)src;
      float4 b = *(const float4*)(src + 4);
      f16x8 vv;
      vv[0]=(f16)a.x; vv[1]=(f16)a.y; vv[2]=(f16)a.z; vv[3]=(f16)a.w;
      vv[4]=(f16)b.x; vv[5]=(f16)b.y; vv[6]=(f16)b.z; vv[7]=(f16)b.w;
      *(f16x8*)(ktile + r * D_DIM + ((kd ^ (r & 15)) * 8)) = vv;
    }
  }

  // ---- V: fp32 -> f16 transposed tile [d(128)][chunk'(8)][8], chunk' = kc^(d&7)
  {
    const int rq = t >> 4;
    const int dg = t & 15;
    const float* base = v + (((size_t)bh * S_LEN + jt * 64 + rq * 4) * D_DIM + dg * 8);
    float rows[4][8];
#pragma unroll
    for (int rr = 0; rr < 4; ++rr) {
      float4 aa = *(const float4*)(base + rr * D_DIM);
      float4 bb = *(const float4*)(base + rr * D_DIM + 4);
      rows[rr][0]=aa.x; rows[rr][1]=aa.y; rows[rr][2]=aa.z; rows[rr][3]=aa.w;
      rows[rr][4]=bb.x; rows[rr][5]=bb.y; rows[rr][6]=bb.z; rows[rr][7]=bb.w;
    }
    const int kc = rq >> 1;
    const int kk = (rq & 1) * 4;
#pragma unroll
    for (int dd0 = 0; dd0 < 8; ++dd0) {
      int dd = (dd0 + dg) & 7;
      int d  = dg * 8 + dd;
      f16x4 p;
      p[0]=(f16)rows[0][dd]; p[1]=(f16)rows[1][dd];
      p[2]=(f16)rows[2][dd]; p[3]=(f16)rows[3][dd];
      *(f16x4*)(Vimg + d * 64 + ((kc ^ dd) * 8) + kk) = p;
    }
    __syncthreads();
    f16* vtile = vtw + ((size_t)bh * NKT + jt) * (size_t)(D_DIM * 64);
#pragma unroll
    for (int i = 0; i < 4; ++i) {
      int idx = i * 256 + t;
      *(f16x8*)(vtile + idx * 8) = *(const f16x8*)(Vimg + idx * 8);
    }
  }
}

// ---- R8: 32x32 swapped-QK datapath on the proven R5 scheduler.
// 128-thr blocks, 2 waves x 32 Q-rows (64-row tile, same item map as R5).
// S^T = K Q^T via mfma_f32_32x32x16_f16:
//   A = K: m=kv=lane&31 (+32*t2), k=(lane>>5)*8+j  -> Klds read, same swizzle
//   B = Q: n=q=lane&31, k=(lane>>5)*8+j            -> registers (qf[8])
//   C/D:   col(lane&31)=q, row=(reg&3)+8*(reg>>2)+4*hi = kv   [m74/m101]
// => lane owns HALF the P-row (32 of 64 kv) of q-row (lane&31); partner
//    lane^32 owns the rest. Softmax: 31-op tree + 1 shfl_xor(32).
// PV: O += P V, A = P assembled IN-REGISTER (Plds eliminated):
//   af[ks] needs P[q][ks*16+hi*8+{0..7}]; own pairs at rg=(ks&1)*2+hi,
//   partner pairs via shfl_xor(32) of rg=(ks&1)*2+1-hi (index-verified).
//   B = V^T from Vlds, row d=dtile*32+ql, chunk (ks*2+hi)^(d&7) (same image).
// MFMA count and K/V ds_reads HALVE per Q-row; Plds traffic+conflicts gone.
__global__ __launch_bounds__(128) void attn_kernel(const float* __restrict__ q,
                                                   const f16* __restrict__ kw,
                                                   const f16* __restrict__ vtw,
                                                   const float* __restrict__ am,
                                                   const float* __restrict__ hm,
                                                   float* __restrict__ out) {
  __shared__ f16 Klds[64 * 128];   // 16 KB: K tile, swizzled (prep layout)
  __shared__ f16 Vlds[128 * 64];   // 16 KB: V^T tile, swizzled (prep layout)
  __shared__ int sh_item;

  const int grp  = blockIdx.x & (NGRP - 1);
  const int t    = threadIdx.x;
  const int w    = t >> 6;        // wave 0/1: rows w*32 .. w*32+31
  const int lane = t & 63;
  const int ql   = lane & 31;     // q-col / K-row-low / V d-col-low
  const int hi   = lane >> 5;     // k-subgroup / kv-half selector

  for (;;) {
    if (t == 0) sh_item = atomicAdd(&g_counters[grp], 1);
    __syncthreads();
    const int item = sh_item;
    if (item >= ITEMS_PER_GRP) break;

    const int qi = 31 - (item >> 2);      // LPT: heaviest first (R5-proven)
    const int bh = grp * 4 + (item & 3);  // group-local bh -> L2 locality
    const int b  = bh >> 4;
    const int h  = bh & 15;
    const int qb = qi * 64;
    const int qin = w * 32 + ql;          // q row within the 64-row tile

    // Q fragments (pre-scaled by log2e): qf[ks] = Q[qrow][ks*16+hi*8 .. +7]
    f16x8 qf[8];
    {
      const float* qsrc = q + (((size_t)bh * S_LEN + qb + qin) * D_DIM + hi * 8);
#pragma unroll
      for (int ks = 0; ks < 8; ++ks) {
        float4 a  = *(const float4*)(qsrc + ks * 16);
        float4 bb = *(const float4*)(qsrc + ks * 16 + 4);
        f16x8 vv;
        vv[0]=(f16)(a.x*LOG2E);  vv[1]=(f16)(a.y*LOG2E);  vv[2]=(f16)(a.z*LOG2E);  vv[3]=(f16)(a.w*LOG2E);
        vv[4]=(f16)(bb.x*LOG2E); vv[5]=(f16)(bb.y*LOG2E); vv[6]=(f16)(bb.z*LOG2E); vv[7]=(f16)(bb.w*LOG2E);
        qf[ks] = vv;
      }
    }

    const float hmv  = hm[h];
    const float* amp = am + (size_t)b * S_LEN;
    const f16* ktiles = kw  + (size_t)bh * NKT * (64 * 128);
    const f16* vtiles = vtw + (size_t)bh * NKT * (64 * 128);

    f32x16 oacc[4];   // [dtile]: O[row=(reg&3)+8*(reg>>2)+4*hi][d=dtile*32+ql]
#pragma unroll
    for (int dt = 0; dt < 4; ++dt)
#pragma unroll
      for (int r = 0; r < 16; ++r) oacc[dt][r] = 0.f;
    float mrow = -INFINITY;   // running max for q-row (qb + qin); symmetric across partner
    float lrow = 0.f;         // PARTIAL sum (this lane's 32 kv); partner holds rest

    for (int j = 0; j <= qi; ++j) {
      __syncthreads();   // (A) prev tile reads done
      {
        const f16* kg = ktiles + (size_t)j * (64 * 128);
        const f16* vg = vtiles + (size_t)j * (64 * 128);
#pragma unroll
        for (int i = 0; i < 8; ++i) async_cp16(kg + (i * 128 + t) * 8, Klds + (i * 128 + t) * 8);
#pragma unroll
        for (int i = 0; i < 8; ++i) async_cp16(vg + (i * 128 + t) * 8, Vlds + (i * 128 + t) * 8);
      }
      // attn_mask for this lane's 32 kv rows: kv = t2*32 + rg*8 + hi*4 + {0..3}
      float4 amv[2][4];
#pragma unroll
      for (int t2 = 0; t2 < 2; ++t2)
#pragma unroll
        for (int rg = 0; rg < 4; ++rg)
          amv[t2][rg] = *(const float4*)(amp + j * 64 + t2 * 32 + rg * 8 + hi * 4);
      __syncthreads();   // (B) drains vmcnt(0): K,V in LDS; amv in regs

      // S^T = K (Q*log2e)^T : two 32x32 tiles (kv 0..31, 32..63)
      f32x16 s0, s1;
#pragma unroll
      for (int r = 0; r < 16; ++r) { s0[r] = 0.f; s1[r] = 0.f; }
#pragma unroll
      for (int ks = 0; ks < 8; ++ks) {
        const f16x8 kf0 = *(const f16x8*)(Klds + ql * 128 + (((ks * 2 + hi) ^ (ql & 15)) * 8));
        s0 = __builtin_amdgcn_mfma_f32_32x32x16_f16(kf0, qf[ks], s0, 0, 0, 0);
        const f16x8 kf1 = *(const f16x8*)(Klds + (32 + ql) * 128 + (((ks * 2 + hi) ^ (ql & 15)) * 8));
        s1 = __builtin_amdgcn_mfma_f32_32x32x16_f16(kf1, qf[ks], s1, 0, 0, 0);
      }

      if (j == qi) {   // causal mask, diagonal tile: mask kv_in > qin
#pragma unroll
        for (int reg = 0; reg < 16; ++reg) {
          const int kv0 = (reg & 3) + 8 * (reg >> 2);   // +4*hi (+32 for s1)
          if (kv0 + 4 * hi > qin)      s0[reg] = -INFINITY;
          if (32 + kv0 + 4 * hi > qin) s1[reg] = -INFINITY;
        }
      }
      // additive mask (exp2 base): s += amv * log2e
#pragma unroll
      for (int rg = 0; rg < 4; ++rg) {
        const float4 a0 = amv[0][rg], a1 = amv[1][rg];
        s0[rg*4+0] = fmaf(a0.x, LOG2E, s0[rg*4+0]);
        s0[rg*4+1] = fmaf(a0.y, LOG2E, s0[rg*4+1]);
        s0[rg*4+2] = fmaf(a0.z, LOG2E, s0[rg*4+2]);
        s0[rg*4+3] = fmaf(a0.w, LOG2E, s0[rg*4+3]);
        s1[rg*4+0] = fmaf(a1.x, LOG2E, s1[rg*4+0]);
        s1[rg*4+1] = fmaf(a1.y, LOG2E, s1[rg*4+1]);
        s1[rg*4+2] = fmaf(a1.z, LOG2E, s1[rg*4+2]);
        s1[rg*4+3] = fmaf(a1.w, LOG2E, s1[rg*4+3]);
      }

      // softmax: balanced tree over 32 in-lane values + 1 partner shuffle
      float m4[8];
#pragma unroll
      for (int g = 0; g < 4; ++g) {
        m4[g]   = fmaxf(fmaxf(s0[g*4+0], s0[g*4+1]), fmaxf(s0[g*4+2], s0[g*4+3]));
        m4[4+g] = fmaxf(fmaxf(s1[g*4+0], s1[g*4+1]), fmaxf(s1[g*4+2], s1[g*4+3]));
      }
      float m16 = fmaxf(fmaxf(fmaxf(m4[0], m4[1]), fmaxf(m4[2], m4[3])),
                        fmaxf(fmaxf(m4[4], m4[5]), fmaxf(m4[6], m4[7])));
      m16 = fmaxf(m16, __shfl_xor(m16, 32));   // full row max (symmetric)

      // T13 defer-max: rescale only when some row's max grew by > 8
      if (!__all(m16 <= mrow + 8.0f)) {
        float mnew  = fmaxf(mrow, m16);
        float alpha = exp2f(mrow - mnew);
        mrow = mnew;
        lrow *= alpha;
        // alpha for O-row rho lives at lane ql==rho (both halves identical)
        float av[16];
#pragma unroll
        for (int reg = 0; reg < 16; ++reg)
          av[reg] = __shfl(alpha, (reg & 3) + 8 * (reg >> 2) + 4 * hi);
#pragma unroll
        for (int dt = 0; dt < 4; ++dt)
#pragma unroll
          for (int reg = 0; reg < 16; ++reg) oacc[dt][reg] *= av[reg];
      }

      // exp2 + pairwise partial sum (this lane's 32 kv)
      float ps = 0.f;
#pragma unroll
      for (int g = 0; g < 4; ++g) {
        s0[g*4+0]=exp2f(s0[g*4+0]-mrow); s0[g*4+1]=exp2f(s0[g*4+1]-mrow);
        s0[g*4+2]=exp2f(s0[g*4+2]-mrow); s0[g*4+3]=exp2f(s0[g*4+3]-mrow);
        s1[g*4+0]=exp2f(s1[g*4+0]-mrow); s1[g*4+1]=exp2f(s1[g*4+1]-mrow);
        s1[g*4+2]=exp2f(s1[g*4+2]-mrow); s1[g*4+3]=exp2f(s1[g*4+3]-mrow);
        ps += ((s0[g*4+0]+s0[g*4+1]) + (s0[g*4+2]+s0[g*4+3]))
            + ((s1[g*4+0]+s1[g*4+1]) + (s1[g*4+2]+s1[g*4+3]));
      }
      lrow += ps;

      // pack P: cc[t2][rg][0]=pk(kv base t2*32+8rg+4hi +{0,1}), [1]=+{2,3}
      uint32_t cc[2][4][2];
#pragma unroll
      for (int rg = 0; rg < 4; ++rg) {
        cc[0][rg][0] = pk2(s0[rg*4+0], s0[rg*4+1]);
        cc[0][rg][1] = pk2(s0[rg*4+2], s0[rg*4+3]);
        cc[1][rg][0] = pk2(s1[rg*4+0], s1[rg*4+1]);
        cc[1][rg][1] = pk2(s1[rg*4+2], s1[rg*4+3]);
      }

      // assemble A-frags: af[ks] = P[q][ks*16+hi*8+{0..7}]
      //   own pairs:  rg = (ks&1)*2 + hi      (kv base ks*16 + 8*hi + 4*hi')
      //   send pairs: rg = (ks&1)*2 + 1 - hi  (what the partner needs)
      //   word order: hi==0 -> [own0,own1,recv0,recv1]; hi==1 -> [recv,recv,own,own]
      f16x8 af[4];
#pragma unroll
      for (int ks = 0; ks < 4; ++ks) {
        const int t2  = ks >> 1;
        const int rgl = (ks & 1) * 2;
        uint32_t oA = hi ? cc[t2][rgl+1][0] : cc[t2][rgl][0];
        uint32_t oB = hi ? cc[t2][rgl+1][1] : cc[t2][rgl][1];
        uint32_t sA = hi ? cc[t2][rgl][0]   : cc[t2][rgl+1][0];
        uint32_t sB = hi ? cc[t2][rgl][1]   : cc[t2][rgl+1][1];
        uint32_t xA = (uint32_t)__shfl_xor((int)sA, 32);
        uint32_t xB = (uint32_t)__shfl_xor((int)sB, 32);
        uint32_t u[4];
        u[0] = hi ? xA : oA;
        u[1] = hi ? xB : oB;
        u[2] = hi ? oA : xA;
        u[3] = hi ? oB : xB;
        __builtin_memcpy(&af[ks], u, 16);
      }

      // O += P V : B = V^T rows d=dtile*32+ql, kv chunk (ks*2+hi)^(d&7)
#pragma unroll
      for (int dt = 0; dt < 4; ++dt) {
        const int drow = dt * 32 + ql;
#pragma unroll
        for (int ks = 0; ks < 4; ++ks) {
          const f16x8 bf = *(const f16x8*)(Vlds + drow * 64 + (((ks * 2 + hi) ^ (drow & 7)) * 8));
          oacc[dt] = __builtin_amdgcn_mfma_f32_32x32x16_f16(af[ks], bf, oacc[dt], 0, 0, 0);
        }
      }
    }

    // epilogue: full l = own + partner partial; out = hm * O / l
    lrow += __shfl_xor(lrow, 32);
    const float linv = hmv / lrow;
    float* ob = out + (((size_t)bh * S_LEN + qb + w * 32) * D_DIM);
#pragma unroll
    for (int reg = 0; reg < 16; ++reg) {
      const int row = (reg & 3) + 8 * (reg >> 2) + 4 * hi;
      const float rv = __shfl(linv, row);   // linv identical on both halves
#pragma unroll
      for (int dt = 0; dt < 4; ++dt)
        ob[row * D_DIM + dt * 32 + ql] = oacc[dt][reg] * rv;
    }
  }
}

extern "C" void kernel_launch(void* const* d_in, const int* in_sizes, int n_in,
                              void* d_out, int out_size, void* d_ws, size_t ws_size,
                              hipStream_t stream) {
  const float* q  = (const float*)d_in[0];
  const float* k  = (const float*)d_in[1];
  const float* v  = (const float*)d_in[2];
  const float* am = (const float*)d_in[3];
  const float* hm = (const float*)d_in[4];
  float* out = (float*)d_out;

  f16* kw  = (f16*)d_ws;                              // 16.78 MB
  f16* vtw = kw + (size_t)BHN * S_LEN * D_DIM;        // 16.78 MB

  prep_kernel<<<1024, 256, 0, stream>>>(k, v, kw, vtw);
  attn_kernel<<<768, 128, 0, stream>>>(q, kw, vtw, am, hm, out);
}